// Round 9
// baseline (835.772 us; speedup 1.0000x reference)
//
#include <hip/hip_runtime.h>
#include <math.h>

// N=16384, IN=512, HID=256, E=262144.
// Z = adj @ (X@W), both GEMMs via fp16 split-2 MFMA (a=a1+a2, b=b1+b2;
// products a1b1+a1b2+a2b1). R7/R8: ZERO LDS, ZERO barriers -- A fragments
// load directly from global (coalesced 32B/lane) and split in-register via
// v_cvt_pkrtz; B fragments pre-formatted fragment-ready (global->VGPR).
// adj read exactly once (BN=256, split-K=2): HBM floor 1.07 GB ~ 170 us.
// R8 fix: cvt_pkrtz returns __fp16-vector, not _Float16-vector (bit_cast).

typedef _Float16 half8v __attribute__((ext_vector_type(8)));
typedef __fp16   fp16x2 __attribute__((ext_vector_type(2)));
typedef __attribute__((ext_vector_type(4))) float floatx4;

#define NM_ (16384L * 256L)

// ---- RNE split (prep kernels; exact residual in f32) ----
static __device__ __forceinline__ void split2_pair_f16(float x0, float x1,
                                                       unsigned& q1, unsigned& q2) {
  _Float16 h0 = (_Float16)x0, h1 = (_Float16)x1;
  float r0 = x0 - (float)h0, r1 = x1 - (float)h1;
  _Float16 g0 = (_Float16)r0, g1 = (_Float16)r1;
  q1 = ((unsigned)__builtin_bit_cast(unsigned short, h1) << 16) |
       __builtin_bit_cast(unsigned short, h0);
  q2 = ((unsigned)__builtin_bit_cast(unsigned short, g1) << 16) |
       __builtin_bit_cast(unsigned short, g0);
}

// ---- RTZ in-register split: 8 f32 -> (a0, a1) fp16, ~3 VALU/pair ----
static __device__ __forceinline__ void split8(const float* __restrict__ x,
                                              half8v& a0, half8v& a1) {
  union U { unsigned u[4]; half8v h; } u0, u1;
#pragma unroll
  for (int p = 0; p < 4; ++p) {
    fp16x2 h = __builtin_amdgcn_cvt_pkrtz(x[2 * p], x[2 * p + 1]);
    float r0 = x[2 * p]     - (float)h[0];   // exact
    float r1 = x[2 * p + 1] - (float)h[1];
    fp16x2 g = __builtin_amdgcn_cvt_pkrtz(r0, r1);
    u0.u[p] = __builtin_bit_cast(unsigned, h);
    u1.u[p] = __builtin_bit_cast(unsigned, g);
  }
  a0 = u0.h; a1 = u1.h;
}

// ---- W[512][256] -> fragment-ready split WT: [s][kt(16)][c(4)][n(256)][8] ----
__global__ __launch_bounds__(256)
void w_split(const float* __restrict__ W, unsigned short* __restrict__ WT)
{
  const int b  = blockIdx.x;          // 64 blocks
  const int kt = b >> 2, c = b & 3;
  const int n  = threadIdx.x;
  const int k0 = kt * 32 + c * 8;
  float x[8];
#pragma unroll
  for (int j = 0; j < 8; ++j) x[j] = W[(k0 + j) * 256 + n];
  unsigned q1[4], q2[4];
#pragma unroll
  for (int p = 0; p < 4; ++p)
    split2_pair_f16(x[2 * p], x[2 * p + 1], q1[p], q2[p]);
  const long o = ((long)(kt * 4 + c) * 256 + n) * 8;
  *(uint4*)&WT[o]          = make_uint4(q1[0], q1[1], q1[2], q1[3]);
  *(uint4*)&WT[o + 131072] = make_uint4(q2[0], q2[1], q2[2], q2[3]);
}

// ---- GEMM1: XW = X @ W, LDS-free fragment-direct fp16 split-2 MFMA ----
__global__ __launch_bounds__(256, 2)
void gemm_xw(const float* __restrict__ X, const unsigned short* __restrict__ WT,
             float* __restrict__ XW)
{
  const int tid  = threadIdx.x;
  const int lane = tid & 63;
  const int w    = tid >> 6;
  const int wm = w >> 1, wn = w & 1;
  const long m0 = (long)(blockIdx.x >> 1) * 128;
  const long n0 = (long)(blockIdx.x & 1) * 128;
  const int fr = lane & 15, kc = lane >> 4;

  const unsigned short* Bq = WT + (long)kc * 2048 + ((long)n0 + wn * 64 + fr) * 8;

  const float* ap[4];
#pragma unroll
  for (int fm = 0; fm < 4; ++fm)
    ap[fm] = X + (m0 + wm * 64 + fm * 16 + fr) * 512L + kc * 8;

  floatx4 acc[4][4];
#pragma unroll
  for (int i = 0; i < 4; ++i)
#pragma unroll
    for (int j = 0; j < 4; ++j) acc[i][j] = (floatx4)0.f;

  for (int t = 0; t < 16; ++t) {
    half8v bf0[4], bf1[4];
#pragma unroll
    for (int fn = 0; fn < 4; ++fn) {
      bf0[fn] = *(const half8v*)(Bq + (long)t * 8192 + fn * 128);
      bf1[fn] = *(const half8v*)(Bq + (long)t * 8192 + fn * 128 + 131072);
    }
#pragma unroll
    for (int fm = 0; fm < 4; ++fm) {
      float x[8];
      *(float4*)&x[0] = *(const float4*)(ap[fm] + t * 32);
      *(float4*)&x[4] = *(const float4*)(ap[fm] + t * 32 + 4);
      half8v a0, a1;
      split8(x, a0, a1);
#pragma unroll
      for (int fn = 0; fn < 4; ++fn) {
        floatx4 d = acc[fm][fn];
        d = __builtin_amdgcn_mfma_f32_16x16x32_f16(a0, bf0[fn], d, 0, 0, 0);
        d = __builtin_amdgcn_mfma_f32_16x16x32_f16(a0, bf1[fn], d, 0, 0, 0);
        d = __builtin_amdgcn_mfma_f32_16x16x32_f16(a1, bf0[fn], d, 0, 0, 0);
        acc[fm][fn] = d;
      }
    }
  }
#pragma unroll
  for (int fm = 0; fm < 4; ++fm)
#pragma unroll
    for (int fn = 0; fn < 4; ++fn) {
      const long col  = n0 + wn * 64 + fn * 16 + fr;
      const long rowb = m0 + wm * 64 + fm * 16 + kc * 4;
#pragma unroll
      for (int j = 0; j < 4; ++j)
        XW[(rowb + j) * 256 + col] = acc[fm][fn][j];
    }
}

// ---- transpose + split2 XW -> fragment-ready: [s][kt(512)][c(4)][n(256)][8] ----
__global__ __launch_bounds__(256)
void transpose_split(const float* __restrict__ XW,
                     unsigned short* __restrict__ X1,
                     unsigned short* __restrict__ X2)
{
  __shared__ float T[64][65];
  const int tid = threadIdx.x;
  const long kb = (long)blockIdx.x * 64;   // XW row (k) tile
  const long nb = (long)blockIdx.y * 64;   // XW col (n) tile

#pragma unroll
  for (int i = 0; i < 4; ++i) {
    int idx = tid + 256 * i;
    int r = idx >> 4, c4 = (idx & 15) * 4;
    float4 v = *(const float4*)&XW[(kb + r) * 256 + nb + c4];
    T[r][c4 + 0] = v.x; T[r][c4 + 1] = v.y; T[r][c4 + 2] = v.z; T[r][c4 + 3] = v.w;
  }
  __syncthreads();

#pragma unroll
  for (int i = 0; i < 2; ++i) {
    int idx = tid + 256 * i;
    int n = idx >> 3, kq = (idx & 7) * 8;
    float x[8];
#pragma unroll
    for (int j = 0; j < 8; ++j) x[j] = T[kq + j][n];
    unsigned q1[4], q2[4];
#pragma unroll
    for (int p = 0; p < 4; ++p)
      split2_pair_f16(x[2 * p], x[2 * p + 1], q1[p], q2[p]);
    const long gk = kb + kq;
    const long gt = gk >> 5;
    const int  c  = (int)((gk >> 3) & 3);
    const long o  = ((gt * 4 + c) * 256 + (nb + n)) * 8;
    *(uint4*)&X1[o] = make_uint4(q1[0], q1[1], q1[2], q1[3]);
    *(uint4*)&X2[o] = make_uint4(q2[0], q2[1], q2[2], q2[3]);
  }
}

// ---- GEMM2: Z-partials = adj @ XW. LDS-free, barrier-free. ----
// 512 thr (8 waves 2m x 4n), BM=128 BN=256, split-K=2 -> grid 256 (1/CU).
// adj read exactly once. A frags: global 32B/lane + in-reg RTZ split.
// B frags: fragment-ready global (k-window L2-resident chip-wide).
__global__ __launch_bounds__(512, 2)
void gemm_adj(const float* __restrict__ A, const unsigned short* __restrict__ Bg,
              float* __restrict__ P0, float* __restrict__ P1)
{
  const int tid  = threadIdx.x;
  const int lane = tid & 63;
  const int w    = tid >> 6;          // 0..7
  const int wm = w >> 2, wn = w & 3;
  const int bid = blockIdx.x;
  const long m0 = (long)(bid & 127) * 128;
  const int  z  = bid >> 7;
  float* __restrict__ Cp = z ? P1 : P0;
  const int fr = lane & 15, kc = lane >> 4;

  const unsigned short* Bq0 = Bg + (long)z * 2097152 + (long)kc * 2048 +
                              ((long)wn * 64 + fr) * 8;
  const unsigned short* Bq1 = Bq0 + NM_;

  const float* ap[4];
#pragma unroll
  for (int fm = 0; fm < 4; ++fm)
    ap[fm] = A + (m0 + wm * 64 + fm * 16 + fr) * 16384L + (long)z * 8192 + kc * 8;

  floatx4 acc[4][4], accS[4][4];
#pragma unroll
  for (int i = 0; i < 4; ++i)
#pragma unroll
    for (int j = 0; j < 4; ++j) { acc[i][j] = (floatx4)0.f; accS[i][j] = (floatx4)0.f; }

  float  ra[4][8];     // raw A(t) per fm
  half8v bf0[4], bf1[4];

  // prologue: tile 0
#pragma unroll
  for (int fm = 0; fm < 4; ++fm) {
    *(float4*)&ra[fm][0] = *(const float4*)(ap[fm]);
    *(float4*)&ra[fm][4] = *(const float4*)(ap[fm] + 4);
  }
#pragma unroll
  for (int fn = 0; fn < 4; ++fn) {
    bf0[fn] = *(const half8v*)(Bq0 + fn * 128);
    bf1[fn] = *(const half8v*)(Bq1 + fn * 128);
  }

  for (int t = 0; t < 256; ++t) {
    const long ko = (long)((t + 1) & 255) * 32;     // next-tile A offset (wraps)
    const long bo = (long)((t + 1) & 255) * 8192;   // next-tile B offset
#pragma unroll
    for (int fm = 0; fm < 4; ++fm) {
      half8v a0, a1;
      split8(ra[fm], a0, a1);
      // reload ra[fm] for t+1 (regs free after split; ~1 iter of cover)
      *(float4*)&ra[fm][0] = *(const float4*)(ap[fm] + ko);
      *(float4*)&ra[fm][4] = *(const float4*)(ap[fm] + ko + 4);
#pragma unroll
      for (int fn = 0; fn < 4; ++fn) {
        floatx4 d = acc[fm][fn];
        d = __builtin_amdgcn_mfma_f32_16x16x32_f16(a0, bf0[fn], d, 0, 0, 0);
        d = __builtin_amdgcn_mfma_f32_16x16x32_f16(a0, bf1[fn], d, 0, 0, 0);
        d = __builtin_amdgcn_mfma_f32_16x16x32_f16(a1, bf0[fn], d, 0, 0, 0);
        acc[fm][fn] = d;
      }
    }
#pragma unroll
    for (int fn = 0; fn < 4; ++fn) {
      bf0[fn] = *(const half8v*)(Bq0 + bo + fn * 128);
      bf1[fn] = *(const half8v*)(Bq1 + bo + fn * 128);
    }
    if ((t & 31) == 31) {   // chunked accumulation (numerics, as R4-R6)
#pragma unroll
      for (int i = 0; i < 4; ++i)
#pragma unroll
        for (int j = 0; j < 4; ++j) { accS[i][j] += acc[i][j]; acc[i][j] = (floatx4)0.f; }
    }
  }

  // epilogue: C/D layout col=lane&15, row=kc*4+j
#pragma unroll
  for (int fm = 0; fm < 4; ++fm)
#pragma unroll
    for (int fn = 0; fn < 4; ++fn) {
      const long col  = wn * 64 + fn * 16 + fr;
      const long rowb = m0 + wm * 64 + fm * 16 + kc * 4;
#pragma unroll
      for (int j = 0; j < 4; ++j)
        Cp[(rowb + j) * 256 + col] = accS[fm][fn][j];
    }
}

// ---------------- P1 += P0 ----------------
__global__ __launch_bounds__(256)
void reduce_add(const float* __restrict__ P0, float* __restrict__ P1, long n4)
{
  long i = (long)blockIdx.x * 256 + threadIdx.x;
  const long stride = (long)gridDim.x * 256;
  for (; i < n4; i += stride) {
    float4 a = ((const float4*)P0)[i];
    float4 b = ((const float4*)P1)[i];
    b.x += a.x; b.y += a.y; b.z += a.z; b.w += a.w;
    ((float4*)P1)[i] = b;
  }
}

// ---------------- edge scoring ----------------
__global__ __launch_bounds__(256)
void edge_score(const float* __restrict__ Z, const float* __restrict__ w2,
                const int* __restrict__ te, const int* __restrict__ fe,
                int E, float* __restrict__ out)
{
  const long gtid = (long)blockIdx.x * 256 + threadIdx.x;
  const long wid = gtid >> 6;
  const int lane = threadIdx.x & 63;
  if (wid >= 2L * E) return;
  const int* ep = (wid < E) ? (te + 2 * wid) : (fe + 2 * (wid - E));
  const int src = ep[0];
  const int dst = ep[1];
  const float4 a = ((const float4*)(Z + (long)src * 256))[lane];
  const float4 b = ((const float4*)(Z + (long)dst * 256))[lane];
  const float4 w = ((const float4*)w2)[lane];
  float s = a.x * b.x * w.x + a.y * b.y * w.y + a.z * b.z * w.z + a.w * b.w * w.w;
#pragma unroll
  for (int off = 32; off > 0; off >>= 1) s += __shfl_down(s, off);
  if (lane == 0) out[wid] = 1.0f / (1.0f + expf(-s));
}

extern "C" void kernel_launch(void* const* d_in, const int* in_sizes, int n_in,
                              void* d_out, int out_size, void* d_ws, size_t ws_size,
                              hipStream_t stream)
{
  const float* X   = (const float*)d_in[0];
  const float* adj = (const float*)d_in[1];
  const float* W   = (const float*)d_in[2];
  const float* W2  = (const float*)d_in[3];
  const int*   te  = (const int*)d_in[4];
  const int*   fe  = (const int*)d_in[5];

  const int E = in_sizes[4] / 2;

  float* ws = (float*)d_ws;
  float* P0 = ws;                      // also XW (dead before gemm_adj writes)
  float* P1 = ws + NM_;                // final Z
  unsigned short* X1 = (unsigned short*)(ws + 2 * NM_);
  unsigned short* X2 = X1 + NM_;
  unsigned short* WT = X2 + NM_;       // 2 x 512 x 256 shorts = 0.5 MB
  // total ws: 2*NM*4 + 2*NM*2 + 0.5MB ~ 50.9 MB

  dim3 b256(256);
  w_split<<<dim3(64), b256, 0, stream>>>(W, WT);
  gemm_xw<<<dim3(256), b256, 0, stream>>>(X, WT, P0);          // XW -> P0 space
  transpose_split<<<dim3(256, 4), b256, 0, stream>>>(P0, X1, X2);
  gemm_adj<<<dim3(256), dim3(512), 0, stream>>>(adj, X1, P0, P1);
  reduce_add<<<dim3(2048), b256, 0, stream>>>(P0, P1, NM_ / 4);
  const long nwaves = 2L * E;
  const int nblocks = (int)((nwaves + 3) / 4);
  edge_score<<<dim3(nblocks), b256, 0, stream>>>(P1, W2, te, fe, E, (float*)d_out);
}